// Round 2
// baseline (252.102 us; speedup 1.0000x reference)
//
#include <hip/hip_runtime.h>
#include <hip/hip_bf16.h>

// BLAST factorized linear, fused single-pass:
//   T_j[n,r]     = sum_s X[n, j*256+s] * Vt[j,s,r]        (MFMA, swapped: D=[r,n], T stays in regs)
//   u[o][n,r]   += S[o,j,r] * T_j[n,r]                    (VALU fp32, folded into j-loop)
//   out[n,o*256+p] = bias + sum_r u[o][n,r] * U[o,r,p]    (MFMA, swapped: D=[p,n] -> float4 stores)
// One barrier per workgroup. 16 rows/wg, 512 wg, 2 wg/CU.

typedef __bf16 bf16x8 __attribute__((ext_vector_type(8)));
typedef __bf16 bf16x4 __attribute__((ext_vector_type(4)));
typedef float  f32x4  __attribute__((ext_vector_type(4)));

#define IN_DIM  4096
#define OUT_DIM 4096
#define NROWS   8192
#define BJ      16
#define BO      16
#define BS_IN   256
#define BS_OUT  256
#define RANK    128

__device__ __forceinline__ bf16x8 cvt8(f32x4 lo, f32x4 hi) {
  bf16x8 r;
  r[0] = (__bf16)lo[0]; r[1] = (__bf16)lo[1]; r[2] = (__bf16)lo[2]; r[3] = (__bf16)lo[3];
  r[4] = (__bf16)hi[0]; r[5] = (__bf16)hi[1]; r[6] = (__bf16)hi[2]; r[7] = (__bf16)hi[3];
  return r;
}

// prep: Vt (16,256,128) fp32 -> vt_t[j][r][s] bf16 ; U (16,128,256) fp32 -> u_t[o][p][r] bf16
__global__ __launch_bounds__(256) void prep_kernel(
    const float* __restrict__ Vt, const float* __restrict__ U,
    __bf16* __restrict__ vt_t, __bf16* __restrict__ u_t)
{
  const int NV = BJ * RANK * BS_IN;   // 524288
  int idx = blockIdx.x * 256 + threadIdx.x;
  if (idx < NV) {
    int j = idx >> 15;
    int r = (idx >> 8) & (RANK - 1);
    int s = idx & (BS_IN - 1);
    vt_t[idx] = (__bf16)Vt[(j * BS_IN + s) * RANK + r];
  } else {
    int k = idx - NV;
    int o = k >> 15;
    int p = (k >> 7) & (BS_OUT - 1);
    int r = k & (RANK - 1);
    u_t[k] = (__bf16)U[(o * RANK + r) * BS_OUT + p];
  }
}

__global__ __launch_bounds__(256, 2) void blast_main(
    const float* __restrict__ x, const float* __restrict__ S,
    const float* __restrict__ bias,
    const __bf16* __restrict__ vt_t, const __bf16* __restrict__ u_t,
    float* __restrict__ out)
{
  // u_lds[o][n][r] bf16, 8B-slot XOR swizzle: slot' = (r>>2) ^ (n<<1)
  __shared__ __bf16 u_lds[BO * 16 * RANK];   // 64 KB

  const int tid  = threadIdx.x;
  const int lane = tid & 63;
  const int w    = tid >> 6;       // wave 0..3 : owns r-slice [w*32, w*32+32) in A, cols [w*64,..) in B
  const int l15  = lane & 15;
  const int lhi  = lane >> 4;
  const size_t rowbase = (size_t)blockIdx.x * 16;

  // ---------------- Stage A + S-fold ----------------
  // lane holds T[n=l15, r = w*32 + t*16 + lhi*4 + v] in t0/t1 (f32x4 over v)
  f32x4 u_acc[BO][2];
  #pragma unroll
  for (int o = 0; o < BO; ++o) {
    u_acc[o][0] = (f32x4){0.f, 0.f, 0.f, 0.f};
    u_acc[o][1] = (f32x4){0.f, 0.f, 0.f, 0.f};
  }

  const float* xrow = x + (rowbase + l15) * IN_DIM;     // B-operand: col n = l15

  for (int j = 0; j < BJ; ++j) {
    f32x4 t0 = {0.f, 0.f, 0.f, 0.f};
    f32x4 t1 = {0.f, 0.f, 0.f, 0.f};
    const float*  xp = xrow + j * BS_IN;
    const __bf16* vb = vt_t + ((size_t)(j * RANK) + l15) * BS_IN;   // A row = r tile + l15
    #pragma unroll
    for (int ks = 0; ks < 8; ++ks) {                    // K = 256 = 8*32
      const int kc = ks * 32 + lhi * 8;
      const f32x4 xlo = *(const f32x4*)(xp + kc);
      const f32x4 xhi = *(const f32x4*)(xp + kc + 4);
      const bf16x8 xb = cvt8(xlo, xhi);
      const bf16x8 a0 = *(const bf16x8*)(vb + (size_t)(w * 32) * BS_IN + kc);
      const bf16x8 a1 = *(const bf16x8*)(vb + (size_t)(w * 32 + 16) * BS_IN + kc);
      t0 = __builtin_amdgcn_mfma_f32_16x16x32_bf16(a0, xb, t0, 0, 0, 0);
      t1 = __builtin_amdgcn_mfma_f32_16x16x32_bf16(a1, xb, t1, 0, 0, 0);
    }
    // fold: u[o][t] += S[o, j, r] * T_j  (S broadcast across the 16 n-lanes)
    const float* sp = S + (size_t)j * RANK + w * 32 + lhi * 4;
    #pragma unroll
    for (int o = 0; o < BO; ++o) {
      const f32x4 s0 = *(const f32x4*)(sp + o * (BJ * RANK));
      const f32x4 s1 = *(const f32x4*)(sp + o * (BJ * RANK) + 16);
      u_acc[o][0] = s0 * t0 + u_acc[o][0];
      u_acc[o][1] = s1 * t1 + u_acc[o][1];
    }
  }

  // write u to LDS as bf16 (swizzled), one barrier
  #pragma unroll
  for (int o = 0; o < BO; ++o) {
    #pragma unroll
    for (int t = 0; t < 2; ++t) {
      const f32x4 v = u_acc[o][t];
      bf16x4 b;
      b[0] = (__bf16)v[0]; b[1] = (__bf16)v[1]; b[2] = (__bf16)v[2]; b[3] = (__bf16)v[3];
      const int c    = w * 32 + t * 16 + lhi * 4;          // r
      const int slot = ((c >> 2) ^ (l15 << 1));            // 8B slot in [0,32)
      *(bf16x4*)&u_lds[o * 2048 + l15 * 128 + slot * 4] = b;
    }
  }
  __syncthreads();

  // ---------------- Stage B: out[n, o*256+p] = bias + u @ U_o ----------------
  const float* orow = out + (rowbase + l15) * OUT_DIM;
  #pragma unroll 2
  for (int o = 0; o < BO; ++o) {
    // B-operand: u[n=l15][k], swizzled LDS reads
    bf16x8 ub[4];
    #pragma unroll
    for (int ks = 0; ks < 4; ++ks) {
      const int slot = (((ks * 32 + lhi * 8) >> 2) ^ (l15 << 1));
      ub[ks] = *(const bf16x8*)&u_lds[o * 2048 + l15 * 128 + slot * 4];
    }
    // A-operand: U^T rows p = o*256 + w*64 + cf*16 + l15
    const __bf16* ut = u_t + ((size_t)(o * BS_OUT) + w * 64 + l15) * RANK;
    f32x4 acc[4];
    #pragma unroll
    for (int cf = 0; cf < 4; ++cf) acc[cf] = (f32x4){0.f, 0.f, 0.f, 0.f};
    #pragma unroll
    for (int cf = 0; cf < 4; ++cf) {
      #pragma unroll
      for (int ks = 0; ks < 4; ++ks) {
        const bf16x8 af = *(const bf16x8*)(ut + (size_t)(cf * 16) * RANK + ks * 32 + lhi * 8);
        acc[cf] = __builtin_amdgcn_mfma_f32_16x16x32_bf16(af, ub[ks], acc[cf], 0, 0, 0);
      }
    }
    // D = [p, n]: lane stores 4 consecutive p at row n = l15
    #pragma unroll
    for (int cf = 0; cf < 4; ++cf) {
      const int col = o * BS_OUT + w * 64 + cf * 16 + lhi * 4;
      const f32x4 bv = *(const f32x4*)(bias + col);
      *(f32x4*)(orow + col) = acc[cf] + bv;
    }
  }
}

extern "C" void kernel_launch(void* const* d_in, const int* in_sizes, int n_in,
                              void* d_out, int out_size, void* d_ws, size_t ws_size,
                              hipStream_t stream) {
  const float* x    = (const float*)d_in[0];
  const float* S    = (const float*)d_in[1];
  const float* U    = (const float*)d_in[2];
  const float* Vt   = (const float*)d_in[3];
  const float* bias = (const float*)d_in[4];
  float* out = (float*)d_out;

  __bf16* vt_t = (__bf16*)d_ws;                    // 1 MB
  __bf16* u_t  = vt_t + (size_t)BJ * RANK * BS_IN; // 1 MB

  const int prep_elems = BJ * RANK * BS_IN + BO * BS_OUT * RANK; // 1048576
  prep_kernel<<<prep_elems / 256, 256, 0, stream>>>(Vt, U, vt_t, u_t);
  blast_main<<<NROWS / 16, 256, 0, stream>>>(x, S, bias, vt_t, u_t, out);
}